// Round 13
// baseline (231.462 us; speedup 1.0000x reference)
//
#include <hip/hip_runtime.h>
#include <stdint.h>

// lap = I - adj/k, adj = exact k-NN graph (incl. self) under euclidean
// distance with jax.lax.top_k tie-break (lower index wins).
//
// R12: split pipeline (R11) + 4-rows-per-wave register tiling in sel.
//   prep: pack (-2x,-2y,-2z,|p|^2) -> d_ws (bitwise-exact d2, proven R7-R11).
//   sel:  8 waves/block, 4 rows/wave (32 rows/block); one ds_read_b128 per
//         candidate feeds 4 independent d2+INSERT5 chains -> 4x fewer LDS
//         reads per row and 4-way ILP that stays issue-bound even at the
//         ~8 waves/CU residency floor observed since R8. Distance-only
//         top-5 chains; 4 interleaved ballot binary searches; pass2 ballots
//         captured directly into per-row (w0,w1) mask words; ==D remainder
//         by lowest-j rounds; exact serial fallback per bad row (P~7e-4).
//   emit: fillBuffer-shaped grid-stride stream (R11: ~34us, 6.5+ TB/s).

constexpr int Npts = 4096;
constexpr int BLK  = 512;    // sel: 8 waves/block
constexpr int ROWS = 4;      // rows per wave

typedef unsigned long long u64;

__device__ inline u64 u64min(u64 a, u64 b) { return a < b ? a : b; }

__device__ inline u64 wave_min64(u64 v) {
#pragma unroll
    for (int off = 1; off < 64; off <<= 1) {
        u64 o = __shfl_xor(v, off, 64);
        v = u64min(v, o);
    }
    return v;
}

__device__ inline unsigned wave_min32(unsigned v) {
#pragma unroll
    for (int off = 1; off < 64; off <<= 1) {
        unsigned o = __shfl_xor(v, off, 64);
        v = v < o ? v : o;
    }
    return v;
}

__device__ inline unsigned wave_max32(unsigned v) {
#pragma unroll
    for (int off = 1; off < 64; off <<= 1) {
        unsigned o = __shfl_xor(v, off, 64);
        v = v > o ? v : o;
    }
    return v;
}

// d2 from packed (m2x=-2x, m2y=-2y, m2z=-2z, sq); bitwise == reference.
__device__ inline float cand_d2(const float4 pj, float ax, float ay, float az,
                                float sqi) {
    const float u = __fadd_rn(__fadd_rn(__fmul_rn(pj.x, ax), __fmul_rn(pj.y, ay)),
                              __fmul_rn(pj.z, az));        // == -2*rn_dot exactly
    const float v = __fadd_rn(__fadd_rn(sqi, pj.w), u);    // rn(rn(si+sj)-2t)
    return fmaxf(v, 0.0f);   // >= +0.0 -> u32 bit order == float order
}

__global__ __launch_bounds__(256) void prep_kernel(const float* __restrict__ x,
                                                   float4* __restrict__ p,
                                                   int total) {
    const int t = blockIdx.x * 256 + threadIdx.x;
    if (t >= total) return;
    const float bx = x[3 * t], by = x[3 * t + 1], bz = x[3 * t + 2];
    const float sq = __fadd_rn(__fadd_rn(__fmul_rn(bx, bx), __fmul_rn(by, by)),
                               __fmul_rn(bz, bz));
    p[t] = make_float4(-2.0f * bx, -2.0f * by, -2.0f * bz, sq);  // *2 exact
}

__global__ __launch_bounds__(BLK) void sel_kernel(const float* __restrict__ x,
                                                  const float4* __restrict__ pts,
                                                  const int* __restrict__ kptr,
                                                  unsigned* __restrict__ mask) {
    __shared__ float4 pts4[Npts];   // EXACTLY 64 KB

    const int tid  = threadIdx.x;
    const int lane = tid & 63;
    const int wv   = tid >> 6;                          // 0..7
    const int b    = blockIdx.x >> 7;                   // 128 blocks per batch
    const int base = (((blockIdx.x & 127) << 3) | wv) << 2;   // first of 4 rows

    int k = *kptr;
    if (k < 1) k = 1;
    if (k > Npts) k = Npts;

    // ---- stage packed points once per block ----
    const float4* pb = pts + (size_t)b * Npts;
#pragma unroll
    for (int s = 0; s < Npts / BLK; ++s)
        pts4[tid + BLK * s] = pb[tid + BLK * s];
    __syncthreads();

    // ---- this wave's 4 row points (raw coords from x, sq from tile) ----
    const float* xb = x + (size_t)b * (Npts * 3);
    float ax[ROWS], ay[ROWS], az[ROWS], sqi[ROWS];
#pragma unroll
    for (int r = 0; r < ROWS; ++r) {
        const int i = base + r;
        ax[r] = xb[3 * i]; ay[r] = xb[3 * i + 1]; az[r] = xb[3 * i + 2];
        sqi[r] = pts4[i].w;
    }
    const float INF_F = __uint_as_float(0x7f800000u);

    // ---- pass1: per-lane sorted top-5 distances per row (no indices) ----
    float e[ROWS][5];
#pragma unroll
    for (int r = 0; r < ROWS; ++r)
#pragma unroll
        for (int s = 0; s < 5; ++s) e[r][s] = INF_F;

#pragma unroll 2
    for (unsigned c = 0; c < 64; ++c) {
        const float4 pj = pts4[(c << 6) | (unsigned)lane];
#pragma unroll
        for (int r = 0; r < ROWS; ++r) {
            const float d = cand_d2(pj, ax[r], ay[r], az[r], sqi[r]);
            const float n4 = __builtin_amdgcn_fmed3f(e[r][3], e[r][4], d);
            const float n3 = __builtin_amdgcn_fmed3f(e[r][2], e[r][3], d);
            const float n2 = __builtin_amdgcn_fmed3f(e[r][1], e[r][2], d);
            const float n1 = __builtin_amdgcn_fmed3f(e[r][0], e[r][1], d);
            const float n0 = fminf(e[r][0], d);
            e[r][0] = n0; e[r][1] = n1; e[r][2] = n2; e[r][3] = n3; e[r][4] = n4;
        }
    }

    // ---- 4 interleaved ballot binary searches for per-row kth distance ----
    unsigned lo[ROWS], hi[ROWS], nlt[ROWS];
#pragma unroll
    for (int r = 0; r < ROWS; ++r) {
        lo[r]  = wave_min32(__float_as_uint(e[r][0]));   // count(< lo) == 0 < k
        hi[r]  = (k <= 64) ? wave_max32(__float_as_uint(e[r][0])) + 1u
                           : 0x7f800001u;
        nlt[r] = 0;
    }
    while ((hi[0] - lo[0] > 1u) | (hi[1] - lo[1] > 1u) |
           (hi[2] - lo[2] > 1u) | (hi[3] - lo[3] > 1u)) {
#pragma unroll
        for (int r = 0; r < ROWS; ++r) {
            if (hi[r] - lo[r] > 1u) {                    // wave-uniform branch
                const unsigned mid = (lo[r] + hi[r]) >> 1;
                const unsigned cnt =
                    (unsigned)__popcll(__ballot(__float_as_uint(e[r][0]) < mid)) +
                    (unsigned)__popcll(__ballot(__float_as_uint(e[r][1]) < mid)) +
                    (unsigned)__popcll(__ballot(__float_as_uint(e[r][2]) < mid)) +
                    (unsigned)__popcll(__ballot(__float_as_uint(e[r][3]) < mid)) +
                    (unsigned)__popcll(__ballot(__float_as_uint(e[r][4]) < mid));
                if (cnt < (unsigned)k) { lo[r] = mid; nlt[r] = cnt; }
                else hi[r] = mid;
            }
        }
    }
    bool bad[ROWS];
#pragma unroll
    for (int r = 0; r < ROWS; ++r)
        bad[r] = (__any(__float_as_uint(e[r][4]) <= lo[r]) != 0) || (k > 256);

    // ---- pass2: recompute, capture row masks straight from ballots ----
    // word w of a row's 128-word mask covers j = 32w..32w+31; j=(c<<6)|l ->
    // w = 2c+(l>>5): word `lane` <- ballot at c=lane>>1 (half by lane&1),
    // word `lane+64` <- ballot at c=32+(lane>>1).
    unsigned w0[ROWS], w1[ROWS];
    u64 eqm[ROWS];
#pragma unroll
    for (int r = 0; r < ROWS; ++r) { w0[r] = 0; w1[r] = 0; eqm[r] = 0; }
    const unsigned myc0 = (unsigned)lane >> 1;
    const unsigned myc1 = 32u + ((unsigned)lane >> 1);
    const unsigned mysh = ((unsigned)lane & 1u) << 5;

#pragma unroll 2
    for (unsigned c = 0; c < 64; ++c) {
        const float4 pj = pts4[(c << 6) | (unsigned)lane];
#pragma unroll
        for (int r = 0; r < ROWS; ++r) {
            const float d = cand_d2(pj, ax[r], ay[r], az[r], sqi[r]);
            const unsigned db = __float_as_uint(d);
            const u64 B = __ballot(db < lo[r]);
            if (c == myc0) w0[r] = (unsigned)(B >> mysh);
            if (c == myc1) w1[r] = (unsigned)(B >> mysh);
            eqm[r] |= (u64)(db == lo[r]) << c;
        }
    }

    // ---- per row: ==D remainder (typ. 1 round) or exact serial fallback ----
#pragma unroll
    for (int r = 0; r < ROWS; ++r) {
        if (!bad[r]) {
            int rem = k - (int)nlt[r];
            while (rem > 0) {
                const unsigned myj = eqm[r]
                    ? (((unsigned)(__ffsll((long long)eqm[r]) - 1) << 6) |
                       (unsigned)lane)
                    : 0xFFFFFFFFu;
                const unsigned mn = wave_min32(myj);
                if (mn == 0xFFFFFFFFu) break;   // safety (cannot happen if !bad)
                const unsigned word = mn >> 5, bit = mn & 31u;
                if (word == (unsigned)lane)       w0[r] |= 1u << bit;
                if (word == (unsigned)lane + 64u) w1[r] |= 1u << bit;
                if (myj == mn) eqm[r] &= eqm[r] - 1;
                --rem;
            }
        } else {
            w0[r] = 0; w1[r] = 0;
            u64 used = 0;
            for (int t = 0; t < k; ++t) {
                u64 best = ~0ull;
                for (unsigned c = 0; c < 64; ++c) {
                    if (!((used >> c) & 1ull)) {
                        const unsigned j = (c << 6) | (unsigned)lane;
                        const float d = cand_d2(pts4[j], ax[r], ay[r], az[r], sqi[r]);
                        best = u64min(best, ((u64)__float_as_uint(d) << 32) | j);
                    }
                }
                const u64 m = wave_min64(best);
                if (m == ~0ull) break;
                const unsigned j = (unsigned)m;
                const unsigned word = j >> 5, bit = j & 31u;
                if (word == (unsigned)lane)       w0[r] |= 1u << bit;
                if (word == (unsigned)lane + 64u) w1[r] |= 1u << bit;
                if (best == m) used |= 1ull << (j >> 6);
            }
        }
    }

    // ---- store the 4 row masks (coalesced) ----
#pragma unroll
    for (int r = 0; r < ROWS; ++r) {
        unsigned* mrow = mask + ((size_t)(b * Npts + base + r) << 7);
        mrow[lane]      = w0[r];
        mrow[lane + 64] = w1[r];
    }
}

__global__ __launch_bounds__(256) void emit_kernel(const unsigned* __restrict__ mask,
                                                   const int* __restrict__ kptr,
                                                   float4* __restrict__ out,
                                                   int total4) {
    int k = *kptr;
    if (k < 1) k = 1;
    if (k > Npts) k = Npts;
    const float r = 1.0f / sqrtf((float)k);
    const float negrr = -__fmul_rn(r, r);    // -(dinv_i*dinv_j); deg == k exactly

    const int stride = gridDim.x * 256;
    for (int idx = blockIdx.x * 256 + threadIdx.x; idx < total4; idx += stride) {
        const int row = idx >> 10;                 // global row (0 .. B*N)
        const int c4  = idx & 1023;                // float4 within row
        const unsigned word = mask[((size_t)row << 7) + (c4 >> 3)];
        const unsigned nib  = (word >> ((c4 & 7) << 2)) & 0xFu;
        const int i  = row & (Npts - 1);           // row within batch
        const int j0 = c4 << 2;                    // element index of v.x
        float4 v;
        v.x = (nib & 1u) ? negrr : 0.0f;
        v.y = (nib & 2u) ? negrr : 0.0f;
        v.z = (nib & 4u) ? negrr : 0.0f;
        v.w = (nib & 8u) ? negrr : 0.0f;
        v.x = __fadd_rn(v.x, (j0 + 0 == i) ? 1.0f : 0.0f);
        v.y = __fadd_rn(v.y, (j0 + 1 == i) ? 1.0f : 0.0f);
        v.z = __fadd_rn(v.z, (j0 + 2 == i) ? 1.0f : 0.0f);
        v.w = __fadd_rn(v.w, (j0 + 3 == i) ? 1.0f : 0.0f);
        out[idx] = v;
    }
}

extern "C" void kernel_launch(void* const* d_in, const int* in_sizes, int n_in,
                              void* d_out, int out_size, void* d_ws, size_t ws_size,
                              hipStream_t stream) {
    const float* x    = (const float*)d_in[0];
    const int*   kptr = (const int*)d_in[1];
    float*       out  = (float*)d_out;
    const int total = in_sizes[0] / 3;               // B * Npts points
    const int B     = total / Npts;

    float4*   pts  = (float4*)d_ws;                              // 256 KB
    unsigned* mask = (unsigned*)((char*)d_ws + (1u << 20));      // 8 MB @ +1MB

    hipLaunchKernelGGL(prep_kernel, dim3((total + 255) / 256), dim3(256), 0, stream,
                       x, pts, total);
    hipLaunchKernelGGL(sel_kernel, dim3(B * (Npts / 32)), dim3(BLK), 0, stream,
                       x, pts, kptr, mask);
    const int total4 = B * Npts * (Npts / 4);
    hipLaunchKernelGGL(emit_kernel, dim3(2048), dim3(256), 0, stream,
                       mask, kptr, (float4*)out, total4);
}